// Round 12
// baseline (388.395 us; speedup 1.0000x reference)
//
#include <hip/hip_runtime.h>

#define FS    5
#define NTAP  25
#define Cc    32
#define CG    8
#define Hc    128
#define Wc    128
#define HW    (Hc * Wc)

#define TH      8
#define TW      64
#define HALO_H  12
#define HALO_W  72
#define PLANE   (HALO_H * HALO_W)
#define F4_PER_PLANE (PLANE / 4)
#define F4_TOTAL     (CG * F4_PER_PLANE)
#define LDS_BYTES    (CG * PLANE * 4)

#define P1_REP 5
#define P2_REP 5
#define P3_REP 30
#define P4_REP 8

__device__ __attribute__((aligned(16))) float ZERO4[4];

__device__ __forceinline__ void gload_lds16(const float* g, float* lds) {
    __builtin_amdgcn_global_load_lds(
        (const __attribute__((address_space(1))) void*)g,
        (__attribute__((address_space(3))) void*)lds, 16, 0, 0);
}

// ================= REAL kernel 1: gen (unchanged R11) =================
__global__ __launch_bounds__(256) void gen_kernel(
    const float* __restrict__ x, const float* __restrict__ wg,
    const float* __restrict__ bg, float* __restrict__ filt)
{
    const int p = blockIdx.x * 256 + threadIdx.x;
    const int b = blockIdx.y;

    const float* xb = x + (size_t)b * Cc * HW + p;
    float xv[Cc];
#pragma unroll
    for (int c = 0; c < Cc; ++c) xv[c] = xb[(size_t)c * HW];

    float f[NTAP];
#pragma unroll
    for (int t = 0; t < NTAP; ++t) f[t] = bg[t];

#pragma unroll
    for (int t = 0; t < NTAP; ++t) {
        const float* wr = wg + t * Cc;
#pragma unroll
        for (int c = 0; c < Cc; ++c)
            f[t] = fmaf(wr[c], xv[c], f[t]);
    }

    float* fb = filt + (size_t)b * NTAP * HW + p;
#pragma unroll
    for (int t = 0; t < NTAP; ++t) fb[(size_t)t * HW] = f[t];
}

// ================= REAL kernel 2: apply (unchanged R11) =================
__global__ __launch_bounds__(256, 4) void apply_kernel(
    const float* __restrict__ x, const float* __restrict__ filt,
    float* __restrict__ out)
{
    extern __shared__ float xs[];
    const int tid = threadIdx.x;
    const int bid = blockIdx.x;
    const int ht  = bid & 15;
    const int wt  = (bid >> 4) & 1;
    const int chg = (bid >> 5) & 3;
    const int b   = bid >> 7;
    const int h0  = ht * TH;
    const int w0  = wt * TW;
    const int c0  = chg * CG;

    const float* xo = x + ((size_t)b * Cc + c0) * HW;

#pragma unroll
    for (int k = 0; k < 7; ++k) {
        const int f = k * 256 + tid;
        if (f < F4_TOTAL) {
            const int c  = f / F4_PER_PLANE;
            const int rm = f - c * F4_PER_PLANE;
            const int r  = rm / 18;
            const int c4 = rm - r * 18;
            const int gh = h0 - 2 + r;
            const int gw = w0 - 4 + 4 * c4;
            const bool v = ((unsigned)gh < (unsigned)Hc) &&
                           ((unsigned)gw <= (unsigned)(Wc - 4));
            const float* src = v ? (xo + (size_t)c * HW + gh * Wc + gw) : ZERO4;
            gload_lds16(src, xs + (size_t)k * 1024 + (size_t)(tid >> 6) * 256);
        }
    }

    const int ty = tid >> 5;
    const int tx = tid & 31;
    const int w2 = tx * 2;
    const int centerOff = (h0 + ty) * Wc + (w0 + w2);

    float2 ft[NTAP];
    const float* fb = filt + (size_t)b * NTAP * HW + centerOff;
#pragma unroll
    for (int t = 0; t < NTAP; ++t)
        ft[t] = *reinterpret_cast<const float2*>(fb + (size_t)t * HW);

    asm volatile("s_waitcnt vmcnt(0)" ::: "memory");
    __builtin_amdgcn_sched_barrier(0);
    __builtin_amdgcn_s_barrier();

    float* ob = out + ((size_t)b * Cc + c0) * HW + centerOff;
#pragma unroll
    for (int c = 0; c < CG; ++c) {
        const float* p = xs + c * PLANE + ty * HALO_W + (w2 + 2);
        float ax = 0.f, ay = 0.f;
#pragma unroll
        for (int di = 0; di < FS; ++di) {
            const float* row = p + di * HALO_W;
            const float2 s01 = *reinterpret_cast<const float2*>(row);
            const float2 s23 = *reinterpret_cast<const float2*>(row + 2);
            const float2 s45 = *reinterpret_cast<const float2*>(row + 4);
            const float s0 = s01.x, s1 = s01.y, s2 = s23.x,
                        s3 = s23.y, s4 = s45.x, s5 = s45.y;
            ax = fmaf(ft[di * FS + 0].x, s0, ax);  ay = fmaf(ft[di * FS + 0].y, s1, ay);
            ax = fmaf(ft[di * FS + 1].x, s1, ax);  ay = fmaf(ft[di * FS + 1].y, s2, ay);
            ax = fmaf(ft[di * FS + 2].x, s2, ax);  ay = fmaf(ft[di * FS + 2].y, s3, ay);
            ax = fmaf(ft[di * FS + 3].x, s3, ax);  ay = fmaf(ft[di * FS + 3].y, s4, ay);
            ax = fmaf(ft[di * FS + 4].x, s4, ax);  ay = fmaf(ft[di * FS + 4].y, s5, ay);
        }
        *reinterpret_cast<float2*>(ob + (size_t)c * HW) = make_float2(ax, ay);
    }
}

// ============ PROBE 1: gen, SMEM weights (R11 pattern), x P1_REP ============
__global__ __launch_bounds__(256) void pg_smem(
    const float* __restrict__ x, const float* __restrict__ wg,
    const float* __restrict__ bg, float* __restrict__ ws)
{
    const int p = blockIdx.x * 256 + threadIdx.x;
    const int b = blockIdx.y;
#pragma unroll 1
    for (int rep = 0; rep < P1_REP; ++rep) {
        int p2 = p + rep * 7; if (p2 >= HW) p2 -= HW;     // defeat hoist/DSE
        const float* xb = x + (size_t)b * Cc * HW + p2;
        float xv[Cc];
#pragma unroll
        for (int c = 0; c < Cc; ++c) xv[c] = xb[(size_t)c * HW];
        float f[NTAP];
#pragma unroll
        for (int t = 0; t < NTAP; ++t) f[t] = bg[t];
#pragma unroll
        for (int t = 0; t < NTAP; ++t) {
            const float* wr = wg + t * Cc;
#pragma unroll
            for (int c = 0; c < Cc; ++c) f[t] = fmaf(wr[c], xv[c], f[t]);
        }
        float* fb = ws + (size_t)b * NTAP * HW + p2;
#pragma unroll
        for (int t = 0; t < NTAP; ++t) fb[(size_t)t * HW] = f[t];
    }
}

// ============ PROBE 2: gen, LDS weights, x P2_REP ============
__global__ __launch_bounds__(256) void pg_ldsw(
    const float* __restrict__ x, const float* __restrict__ wg,
    const float* __restrict__ bg, float* __restrict__ ws)
{
    __shared__ float wl[NTAP * Cc];
    const int tid = threadIdx.x;
    for (int k = tid; k < NTAP * Cc; k += 256) wl[k] = wg[k];
    __syncthreads();

    const int p = blockIdx.x * 256 + tid;
    const int b = blockIdx.y;
#pragma unroll 1
    for (int rep = 0; rep < P2_REP; ++rep) {
        int p2 = p + rep * 7; if (p2 >= HW) p2 -= HW;
        const float* xb = x + (size_t)b * Cc * HW + p2;
        float xv[Cc];
#pragma unroll
        for (int c = 0; c < Cc; ++c) xv[c] = xb[(size_t)c * HW];
        float f[NTAP];
#pragma unroll
        for (int t = 0; t < NTAP; ++t) f[t] = bg[t];
#pragma unroll
        for (int t = 0; t < NTAP; ++t) {
            const float* wr = wl + t * Cc;                // LDS, uniform addr
#pragma unroll
            for (int c = 0; c < Cc; ++c) f[t] = fmaf(wr[c], xv[c], f[t]);
        }
        float* fb = ws + (size_t)(32u << 20) / 4 + (size_t)b * NTAP * HW + p2;
#pragma unroll
        for (int t = 0; t < NTAP; ++t) fb[(size_t)t * HW] = f[t];
    }
}

// ============ PROBE 3: gen skeleton, NO weight memory in loop, x P3_REP ============
__global__ __launch_bounds__(256) void pg_now(
    const float* __restrict__ x, const float* __restrict__ bg,
    float* __restrict__ ws)
{
    const int p = blockIdx.x * 256 + threadIdx.x;
    const int b = blockIdx.y;
    float wv25[NTAP];
#pragma unroll
    for (int t = 0; t < NTAP; ++t) wv25[t] = bg[t];       // SGPR-resident fake W

#pragma unroll 1
    for (int rep = 0; rep < P3_REP; ++rep) {
        int p2 = p + rep * 7; if (p2 >= HW) p2 -= HW;
        const float* xb = x + (size_t)b * Cc * HW + p2;
        float xv[Cc];
#pragma unroll
        for (int c = 0; c < Cc; ++c) xv[c] = xb[(size_t)c * HW];
        float f[NTAP];
#pragma unroll
        for (int t = 0; t < NTAP; ++t) f[t] = 0.f;
#pragma unroll
        for (int t = 0; t < NTAP; ++t)
#pragma unroll
            for (int c = 0; c < Cc; ++c) f[t] = fmaf(wv25[t], xv[c], f[t]);
        float* fb = ws + (size_t)(64u << 20) / 4 + (size_t)b * NTAP * HW + p2;
#pragma unroll
        for (int t = 0; t < NTAP; ++t) fb[(size_t)t * HW] = f[t];
    }
}

// ============ PROBE 4: apply (R11), x P4_REP ============
__global__ __launch_bounds__(256, 4) void pa_app(
    const float* __restrict__ x, const float* __restrict__ filt,
    float* __restrict__ ws)
{
    extern __shared__ float xs[];
    const int tid = threadIdx.x;
    const int bid = blockIdx.x;
    const int ht  = bid & 15;
    const int wt  = (bid >> 4) & 1;
    const int chg = (bid >> 5) & 3;
    const int b   = bid >> 7;
    const int h0  = ht * TH;
    const int w0  = wt * TW;
    const int c0  = chg * CG;
    const float* xo = x + ((size_t)b * Cc + c0) * HW;

    const int ty = tid >> 5;
    const int tx = tid & 31;
    const int w2 = tx * 2;
    const int centerOff = (h0 + ty) * Wc + (w0 + w2);

#pragma unroll 1
    for (int rep = 0; rep < P4_REP; ++rep) {
#pragma unroll
        for (int k = 0; k < 7; ++k) {
            const int f = k * 256 + tid;
            if (f < F4_TOTAL) {
                const int c  = f / F4_PER_PLANE;
                const int rm = f - c * F4_PER_PLANE;
                const int r  = rm / 18;
                const int c4 = rm - r * 18;
                const int gh = h0 - 2 + r;
                const int gw = w0 - 4 + 4 * c4;
                const bool v = ((unsigned)gh < (unsigned)Hc) &&
                               ((unsigned)gw <= (unsigned)(Wc - 4));
                const float* src = v ? (xo + (size_t)c * HW + gh * Wc + gw) : ZERO4;
                gload_lds16(src, xs + (size_t)k * 1024 + (size_t)(tid >> 6) * 256);
            }
        }
        float2 ft[NTAP];
        const float* fb = filt + (size_t)b * NTAP * HW + centerOff + (rep & 1);
#pragma unroll
        for (int t = 0; t < NTAP; ++t)
            ft[t] = *reinterpret_cast<const float2*>(fb + (size_t)t * HW);

        asm volatile("s_waitcnt vmcnt(0)" ::: "memory");
        __builtin_amdgcn_sched_barrier(0);
        __builtin_amdgcn_s_barrier();

        float* ob = ws + (size_t)(128u << 20) / 4 +
                    ((size_t)b * Cc + c0) * HW + centerOff + rep;
#pragma unroll
        for (int c = 0; c < CG; ++c) {
            const float* p = xs + c * PLANE + ty * HALO_W + (w2 + 2);
            float ax = 0.f, ay = 0.f;
#pragma unroll
            for (int di = 0; di < FS; ++di) {
                const float* row = p + di * HALO_W;
                const float2 s01 = *reinterpret_cast<const float2*>(row);
                const float2 s23 = *reinterpret_cast<const float2*>(row + 2);
                const float2 s45 = *reinterpret_cast<const float2*>(row + 4);
                const float s0 = s01.x, s1 = s01.y, s2 = s23.x,
                            s3 = s23.y, s4 = s45.x, s5 = s45.y;
                ax = fmaf(ft[di * FS + 0].x, s0, ax);  ay = fmaf(ft[di * FS + 0].y, s1, ay);
                ax = fmaf(ft[di * FS + 1].x, s1, ax);  ay = fmaf(ft[di * FS + 1].y, s2, ay);
                ax = fmaf(ft[di * FS + 2].x, s2, ax);  ay = fmaf(ft[di * FS + 2].y, s3, ay);
                ax = fmaf(ft[di * FS + 3].x, s3, ax);  ay = fmaf(ft[di * FS + 3].y, s4, ay);
                ax = fmaf(ft[di * FS + 4].x, s4, ax);  ay = fmaf(ft[di * FS + 4].y, s5, ay);
            }
            *reinterpret_cast<float2*>(ob + (size_t)c * HW) = make_float2(ax, ay);
        }
        __syncthreads();   // xs WAR before next rep's DMA
    }
}

extern "C" void kernel_launch(void* const* d_in, const int* in_sizes, int n_in,
                              void* d_out, int out_size, void* d_ws, size_t ws_size,
                              hipStream_t stream) {
    const float* x  = (const float*)d_in[0];
    const float* wg = (const float*)d_in[1];
    const float* bg = (const float*)d_in[2];
    float* out = (float*)d_out;
    float* ws  = (float*)d_ws;
    float* filt = ws;                 // 13.1 MB

    gen_kernel<<<dim3(HW / 256, 8), 256, 0, stream>>>(x, wg, bg, filt);
    apply_kernel<<<dim3(1024), 256, LDS_BYTES, stream>>>(x, filt, out);

    if (ws_size >= ((size_t)160 << 20)) {
        pg_smem<<<dim3(HW / 256, 8), 256, 0, stream>>>(x, wg, bg, ws);
        pg_ldsw<<<dim3(HW / 256, 8), 256, 0, stream>>>(x, wg, bg, ws);
        pg_now <<<dim3(HW / 256, 8), 256, 0, stream>>>(x, bg, ws);
        pa_app <<<dim3(1024), 256, LDS_BYTES, stream>>>(x, filt, ws);
    }
}

// Round 13
// 36.165 us; speedup vs baseline: 10.7395x; 10.7395x over previous
//
#include <hip/hip_runtime.h>

#define FS    5
#define NTAP  25
#define Cc    32
#define CGP   8                      // channels per stage group
#define Hc    128
#define Wc    128
#define HW    (Hc * Wc)

#define TH      8
#define TW      64
#define HALO_H  12                   // TH + 4
#define HALO_W  72                   // [w0-4, w0+68): float4-aligned
#define PLANE   (HALO_H * HALO_W)    // 864 floats
#define F4_PER_PLANE (PLANE / 4)     // 216
#define F4_GROUP (CGP * F4_PER_PLANE)   // 1728
#define GRP_FLOATS (CGP * PLANE)        // 6912
#define LDS_BYTES  (2 * GRP_FLOATS * 4) // 55296 B (double buffer)

// zero-initialized device global: OOB lanes' DMA source (16B aligned)
__device__ __attribute__((aligned(16))) float ZERO4[4];

__device__ __forceinline__ void gload_lds16(const float* g, float* lds) {
    __builtin_amdgcn_global_load_lds(
        (const __attribute__((address_space(1))) void*)g,
        (__attribute__((address_space(3))) void*)lds, 16, 0, 0);
}

// One block = one 8x64 tile of one image, ALL 32 channels (zero gen
// redundancy, no filt intermediate). LDS double-buffers 8-channel halo
// groups. Prologue: 32 gen-center loads issued FIRST, then DMA of groups
// 0,1 -> gen's 1600-FMA stream (t-outer, consecutive weights ->
// s_load_dwordx16) runs under the DMA; one sync. Apply g=0..3 with
// refill-under-compute: sync; STAGE(g+2 -> freed buf); STORE(g-1);
// APPLY(g). Stores deferred one phase so they drain with the stage.
__global__ __launch_bounds__(256) void ppdfn_fused(
    const float* __restrict__ x, const float* __restrict__ wg,
    const float* __restrict__ bg, float* __restrict__ out)
{
    extern __shared__ float xs[];     // [2][CGP][PLANE]

    const int tid = threadIdx.x;
    const int bid = blockIdx.x;       // 256 blocks = 16 ht x 2 wt x 8 b
    const int ht  = bid & 15;
    const int wt  = (bid >> 4) & 1;
    const int b   = bid >> 5;
    const int h0  = ht * TH;
    const int w0  = wt * TW;

    const float* xb = x + (size_t)b * Cc * HW;

    const int ty = tid >> 5;          // 0..7
    const int tx = tid & 31;          // 0..31
    const int w2 = tx * 2;
    const int centerOff = (h0 + ty) * Wc + (w0 + w2);

    // DMA-stage channel group cg (8 planes) into buffer buf
    auto STAGE = [&](int cg, int buf) {
#pragma unroll
        for (int k = 0; k < 7; ++k) {
            const int f = k * 256 + tid;
            if (f < F4_GROUP) {                  // k==6: wave-uniform guard
                const int c  = f / F4_PER_PLANE; // /216 (magic mul)
                const int rm = f - c * F4_PER_PLANE;
                const int r  = rm / 18;
                const int c4 = rm - r * 18;
                const int gh = h0 - 2 + r;
                const int gw = w0 - 4 + 4 * c4;
                const bool v = ((unsigned)gh < (unsigned)Hc) &&
                               ((unsigned)gw <= (unsigned)(Wc - 4));
                const float* src = v ? (xb + (size_t)(cg * CGP + c) * HW +
                                        gh * Wc + gw)
                                     : ZERO4;
                gload_lds16(src, xs + (size_t)buf * GRP_FLOATS +
                                 (size_t)k * 1024 + (size_t)(tid >> 6) * 256);
            }
        }
    };

    // ---- prologue: gen-center loads FIRST (independent of DMA), then DMA ----
    float2 cvA[16], cvB[16];
#pragma unroll
    for (int c = 0; c < 16; ++c)
        cvA[c] = *reinterpret_cast<const float2*>(xb + (size_t)c * HW + centerOff);
#pragma unroll
    for (int c = 0; c < 16; ++c)
        cvB[c] = *reinterpret_cast<const float2*>(xb + (size_t)(16 + c) * HW + centerOff);

    STAGE(0, 0);
    STAGE(1, 1);

    // ---- gen: t-outer, weights consecutive per row -> s_load_dwordx16 ----
    float fx[NTAP], fy[NTAP];
#pragma unroll
    for (int t = 0; t < NTAP; ++t) { const float bv = bg[t]; fx[t] = bv; fy[t] = bv; }

#pragma unroll
    for (int t = 0; t < NTAP; ++t) {
        const float* wr = wg + t * Cc;
#pragma unroll
        for (int c = 0; c < 16; ++c) {
            fx[t] = fmaf(wr[c], cvA[c].x, fx[t]);
            fy[t] = fmaf(wr[c], cvA[c].y, fy[t]);
        }
    }
#pragma unroll
    for (int t = 0; t < NTAP; ++t) {
        const float* wr = wg + t * Cc + 16;
#pragma unroll
        for (int c = 0; c < 16; ++c) {
            fx[t] = fmaf(wr[c], cvB[c].x, fx[t]);
            fy[t] = fmaf(wr[c], cvB[c].y, fy[t]);
        }
    }

    __syncthreads();   // drains DMA01 (vmcnt0 before barrier); b0,b1 ready

    // apply 8 channels of group from buffer base into acc (no stores)
    float2 acc0[CGP], acc1[CGP];
    auto APPLYG = [&](const float* bb, float2* acc) {
#pragma unroll
        for (int c = 0; c < CGP; ++c) {
            const float* p = bb + c * PLANE + ty * HALO_W + (w2 + 2);
            float ax = 0.f, ay = 0.f;
#pragma unroll
            for (int di = 0; di < FS; ++di) {
                const float* row = p + di * HALO_W;
                const float2 s01 = *reinterpret_cast<const float2*>(row);
                const float2 s23 = *reinterpret_cast<const float2*>(row + 2);
                const float2 s45 = *reinterpret_cast<const float2*>(row + 4);
                const float s0 = s01.x, s1 = s01.y, s2 = s23.x,
                            s3 = s23.y, s4 = s45.x, s5 = s45.y;
                ax = fmaf(fx[di * FS + 0], s0, ax);  ay = fmaf(fy[di * FS + 0], s1, ay);
                ax = fmaf(fx[di * FS + 1], s1, ax);  ay = fmaf(fy[di * FS + 1], s2, ay);
                ax = fmaf(fx[di * FS + 2], s2, ax);  ay = fmaf(fy[di * FS + 2], s3, ay);
                ax = fmaf(fx[di * FS + 3], s3, ax);  ay = fmaf(fy[di * FS + 3], s4, ay);
                ax = fmaf(fx[di * FS + 4], s4, ax);  ay = fmaf(fy[di * FS + 4], s5, ay);
            }
            acc[c] = make_float2(ax, ay);
        }
    };
    auto STOREG = [&](int g, const float2* acc) {
        float* ob = out + ((size_t)b * Cc + g * CGP) * HW + centerOff;
#pragma unroll
        for (int c = 0; c < CGP; ++c)
            *reinterpret_cast<float2*>(ob + (size_t)c * HW) = acc[c];
    };

    // ---- pipelined apply: stage g+2 and store g-1 under apply g ----
    APPLYG(xs, acc0);                       // g=0 from b0
    __syncthreads();                        // b0 free (nothing in flight)
    STAGE(2, 0);                            // refill b0 (flies under apply1)
    STOREG(0, acc0);                        // stores fly under apply1
    APPLYG(xs + GRP_FLOATS, acc1);          // g=1 from b1
    __syncthreads();                        // drains S2 + st0; b1 free
    STAGE(3, 1);                            // refill b1 (under apply2)
    STOREG(1, acc1);
    APPLYG(xs, acc0);                       // g=2 from b0
    __syncthreads();                        // drains S3 + st1
    STOREG(2, acc0);
    APPLYG(xs + GRP_FLOATS, acc1);          // g=3 from b1
    STOREG(3, acc1);
}

extern "C" void kernel_launch(void* const* d_in, const int* in_sizes, int n_in,
                              void* d_out, int out_size, void* d_ws, size_t ws_size,
                              hipStream_t stream) {
    const float* x  = (const float*)d_in[0];
    const float* wg = (const float*)d_in[1];
    const float* bg = (const float*)d_in[2];
    float* out = (float*)d_out;

    ppdfn_fused<<<dim3(256), 256, LDS_BYTES, stream>>>(x, wg, bg, out);
}

// Round 14
// 28.961 us; speedup vs baseline: 13.4108x; 1.2487x over previous
//
#include <hip/hip_runtime.h>

#define FS    5
#define NTAP  25
#define Cc    32
#define CGP   8                      // channels per LDS group
#define Hc    128
#define Wc    128
#define HW    (Hc * Wc)

#define TH      8
#define TW      64
#define HALO_H  12                   // TH + 4
#define HALO_W  72                   // [w0-4, w0+68): float4-aligned
#define PLANE   (HALO_H * HALO_W)    // 864 floats
#define F4_PER_PLANE (PLANE / 4)     // 216
#define F4_GROUP (CGP * F4_PER_PLANE)   // 1728
#define GRP_FLOATS (CGP * PLANE)        // 6912
#define LDS_BYTES  (2 * GRP_FLOATS * 4) // 55296 B -> 2 blocks/CU

// zero-initialized device global: OOB lanes' DMA source (16B aligned)
__device__ __attribute__((aligned(16))) float ZERO4[4];

__device__ __forceinline__ void gload_lds16(const float* g, float* lds) {
    __builtin_amdgcn_global_load_lds(
        (const __attribute__((address_space(1))) void*)g,
        (__attribute__((address_space(3))) void*)lds, 16, 0, 0);
}

// One block = one 8x64 tile, ONE 16-channel half (gen 2x redundant, apply
// split). Pipeline (counted vmcnt + RAW s_barrier -- __syncthreads would
// emit vmcnt(0) and drain the next group's DMA, the R13 bug):
//   issue 32 gen-center float2 loads (global, L2-coalesces with DMA)
//   issue STAGE(g0->b0), STAGE(g1->b1)          [7 gload_lds each]
//   gen 32ch (t-outer: wg rows consecutive -> s_load_dwordx16)
//   vmcnt(7) + s_barrier        -> b0 ready, g1 still in flight
//   apply g0 (15 b64 LDS reads + 50 FMA + float2 store per channel)
//   vmcnt(0) + s_barrier        -> b1 ready
//   apply g1
__global__ __launch_bounds__(256, 2) void ppdfn_fused(
    const float* __restrict__ x, const float* __restrict__ wg,
    const float* __restrict__ bg, float* __restrict__ out)
{
    extern __shared__ float xs[];     // [2][CGP][PLANE]

    const int tid = threadIdx.x;
    const int bid = blockIdx.x;       // 512 = 16ht x 2wt x 2half x 8b
    const int ht  = bid & 15;
    const int wt  = (bid >> 4) & 1;
    const int hf  = (bid >> 5) & 1;   // channel half (Δbid=32 ≡ 0 mod 8: same XCD)
    const int b   = bid >> 6;
    const int h0  = ht * TH;
    const int w0  = wt * TW;
    const int c0  = hf * 16;          // own 16-channel base

    const float* xb = x + (size_t)b * Cc * HW;

    const int ty = tid >> 5;          // 0..7
    const int tx = tid & 31;          // 0..31
    const int w2 = tx * 2;
    const int centerOff = (h0 + ty) * Wc + (w0 + w2);

    // ---- 1) gen-center loads for ALL 32 channels (in-tile, no OOB) ----
    float2 cvA[16], cvB[16];
#pragma unroll
    for (int c = 0; c < 16; ++c)
        cvA[c] = *reinterpret_cast<const float2*>(xb + (size_t)c * HW + centerOff);
#pragma unroll
    for (int c = 0; c < 16; ++c)
        cvB[c] = *reinterpret_cast<const float2*>(xb + (size_t)(16 + c) * HW + centerOff);

    // ---- 2) DMA-stage own two 8-ch groups ----
    auto STAGE = [&](int cg, int buf) {           // cg: absolute channel base
#pragma unroll
        for (int k = 0; k < 7; ++k) {
            const int f = k * 256 + tid;
            if (f < F4_GROUP) {                   // k==6: wave 3 inactive (safe)
                const int c  = f / F4_PER_PLANE;  // /216 (magic mul)
                const int rm = f - c * F4_PER_PLANE;
                const int r  = rm / 18;
                const int c4 = rm - r * 18;
                const int gh = h0 - 2 + r;
                const int gw = w0 - 4 + 4 * c4;
                const bool v = ((unsigned)gh < (unsigned)Hc) &&
                               ((unsigned)gw <= (unsigned)(Wc - 4));
                const float* src = v ? (xb + (size_t)(cg + c) * HW + gh * Wc + gw)
                                     : ZERO4;
                gload_lds16(src, xs + (size_t)buf * GRP_FLOATS +
                                 (size_t)k * 1024 + (size_t)(tid >> 6) * 256);
            }
        }
    };
    STAGE(c0,     0);
    STAGE(c0 + 8, 1);

    // ---- 3) gen under DMA inflow (t-outer, consecutive weights) ----
    float fx[NTAP], fy[NTAP];
#pragma unroll
    for (int t = 0; t < NTAP; ++t) { const float bv = bg[t]; fx[t] = bv; fy[t] = bv; }

#pragma unroll
    for (int t = 0; t < NTAP; ++t) {
        const float* wr = wg + t * Cc;            // wg[t][0..15] consecutive
#pragma unroll
        for (int c = 0; c < 16; ++c) {
            fx[t] = fmaf(wr[c], cvA[c].x, fx[t]);
            fy[t] = fmaf(wr[c], cvA[c].y, fy[t]);
        }
    }
#pragma unroll
    for (int t = 0; t < NTAP; ++t) {
        const float* wr = wg + t * Cc + 16;       // wg[t][16..31]
#pragma unroll
        for (int c = 0; c < 16; ++c) {
            fx[t] = fmaf(wr[c], cvB[c].x, fx[t]);
            fy[t] = fmaf(wr[c], cvB[c].y, fy[t]);
        }
    }

    // ---- 4) b0 ready: leave g1's 7 DMAs in flight ----
    asm volatile("s_waitcnt vmcnt(7)" ::: "memory");
    __builtin_amdgcn_sched_barrier(0);
    __builtin_amdgcn_s_barrier();

    // ---- 5) apply group 0 (channels c0..c0+7), stores stream out ----
    auto APPLYG = [&](const float* bb, int cg) {
        float* ob = out + ((size_t)b * Cc + cg) * HW + centerOff;
#pragma unroll
        for (int c = 0; c < CGP; ++c) {
            const float* p = bb + c * PLANE + ty * HALO_W + (w2 + 2);
            float ax = 0.f, ay = 0.f;
#pragma unroll
            for (int di = 0; di < FS; ++di) {
                const float* row = p + di * HALO_W;
                const float2 s01 = *reinterpret_cast<const float2*>(row);
                const float2 s23 = *reinterpret_cast<const float2*>(row + 2);
                const float2 s45 = *reinterpret_cast<const float2*>(row + 4);
                const float s0 = s01.x, s1 = s01.y, s2 = s23.x,
                            s3 = s23.y, s4 = s45.x, s5 = s45.y;
                ax = fmaf(fx[di * FS + 0], s0, ax);  ay = fmaf(fy[di * FS + 0], s1, ay);
                ax = fmaf(fx[di * FS + 1], s1, ax);  ay = fmaf(fy[di * FS + 1], s2, ay);
                ax = fmaf(fx[di * FS + 2], s2, ax);  ay = fmaf(fy[di * FS + 2], s3, ay);
                ax = fmaf(fx[di * FS + 3], s3, ax);  ay = fmaf(fy[di * FS + 3], s4, ay);
                ax = fmaf(fx[di * FS + 4], s4, ax);  ay = fmaf(fy[di * FS + 4], s5, ay);
            }
            *reinterpret_cast<float2*>(ob + (size_t)c * HW) = make_float2(ax, ay);
        }
    };

    APPLYG(xs, c0);

    // ---- 6) b1 ready (drains g1 DMAs + g0 stores; conservative but safe) ----
    asm volatile("s_waitcnt vmcnt(0)" ::: "memory");
    __builtin_amdgcn_sched_barrier(0);
    __builtin_amdgcn_s_barrier();

    // ---- 7) apply group 1 ----
    APPLYG(xs + GRP_FLOATS, c0 + 8);
}

extern "C" void kernel_launch(void* const* d_in, const int* in_sizes, int n_in,
                              void* d_out, int out_size, void* d_ws, size_t ws_size,
                              hipStream_t stream) {
    const float* x  = (const float*)d_in[0];
    const float* wg = (const float*)d_in[1];
    const float* bg = (const float*)d_in[2];
    float* out = (float*)d_out;

    ppdfn_fused<<<dim3(512), 256, LDS_BYTES, stream>>>(x, wg, bg, out);
}